// Round 2
// baseline (21968.159 us; speedup 1.0000x reference)
//
#include <hip/hip_runtime.h>

// ---------------------------------------------------------------------------
// mLSTM persistent-scan kernel for MI355X (gfx950).  B=16,S=512,I=512,H=1024.
// Precision strategy: every bf16 operand is split hi+lo (residual ~2^-18) and
// GEMMs/matvecs use 3-term MFMA (hh + lh + hl) => fp32-quality everywhere.
// Pipeline: wnorm (split weights) -> GEMM mx (fp32) -> GEMM zx (fp32, permuted
// cols) -> persistent scan (320 one-wave blocks: 64 phase-A + 256 phase-B).
// Sync: two monotone counting semaphores (agent-scope atomics + fences).
// ---------------------------------------------------------------------------

typedef __attribute__((ext_vector_type(8))) short   short8;
typedef __attribute__((ext_vector_type(4))) float   float4_;

#define HSZ (16 * 512 * 1024)

__device__ __forceinline__ short f2bf(float x) {
  unsigned u = __float_as_uint(x);
  u += 0x7FFFu + ((u >> 16) & 1u);           // RNE
  return (short)(u >> 16);
}
__device__ __forceinline__ float bf2f(unsigned short s) {
  return __uint_as_float(((unsigned)s) << 16);
}
__device__ __forceinline__ float sigf(float x) { return 1.f / (1.f + __expf(-x)); }
__device__ __forceinline__ float tanhfast(float x) { return 2.f / (1.f + __expf(-2.f * x)) - 1.f; }

__device__ __forceinline__ float4_ mfma16(short8 a, short8 b, float4_ c) {
  return __builtin_amdgcn_mfma_f32_16x16x32_bf16(a, b, c, 0, 0, 0);
}

__device__ __forceinline__ void spin_ge(const unsigned* p, unsigned tgt) {
  while (__hip_atomic_load(p, __ATOMIC_RELAXED, __HIP_MEMORY_SCOPE_AGENT) < tgt)
    __builtin_amdgcn_s_sleep(1);
  __builtin_amdgcn_fence(__ATOMIC_ACQUIRE, "agent");
}
__device__ __forceinline__ void release_inc(unsigned* p) {
  __builtin_amdgcn_fence(__ATOMIC_RELEASE, "agent");
  if (threadIdx.x == 0)
    __hip_atomic_fetch_add(p, 1u, __ATOMIC_RELAXED, __HIP_MEMORY_SCOPE_AGENT);
}

// ---------------------------------------------------------------------------
// Weight-norm: W = v*g/||v||, emitted as hi/lo bf16 planes.
// permute!=0 (Wx): out row r <- src row (r&3)*1024 + (r>>4)*4 + ((r>>2)&3).
// ---------------------------------------------------------------------------
__global__ __launch_bounds__(256) void wnorm_kernel(
    const float* __restrict__ v, const float* __restrict__ g,
    short* __restrict__ outH, short* __restrict__ outL, int cols, int permute)
{
  int r = blockIdx.x, tid = threadIdx.x;
  int src = r;
  if (permute) {
    int bid = r >> 4, jj = (r >> 2) & 3, gg = r & 3;
    src = gg * 1024 + bid * 4 + jj;
  }
  const float* row = v + (size_t)src * cols;
  float s = 0.f;
  for (int c = tid; c < cols; c += 256) { float x = row[c]; s += x * x; }
  #pragma unroll
  for (int off = 32; off; off >>= 1) s += __shfl_down(s, off);
  __shared__ float red[4];
  if ((tid & 63) == 0) red[tid >> 6] = s;
  __syncthreads();
  float tot = red[0] + red[1] + red[2] + red[3];
  float scale = g[src] / sqrtf(tot);
  for (int c = tid; c < cols; c += 256) {
    float wv = row[c] * scale;
    short hh = f2bf(wv);
    outH[(size_t)r * cols + c] = hh;
    outL[(size_t)r * cols + c] = f2bf(wv - bf2f((unsigned short)hh));
  }
}

// ---------------------------------------------------------------------------
// GEMM: Out[8192][NCOLS] (fp32) = X[8192][512] @ W[NCOLS][512]^T, W pre-split.
// x split hi/lo on the fly; 3-term MFMA. BM=128 BN=64 BK=32, 4 waves.
// ---------------------------------------------------------------------------
template <int NCOLS>
__global__ __launch_bounds__(256) void gemm_xw(
    const float* __restrict__ X,
    const short* __restrict__ WH, const short* __restrict__ WL,
    float* __restrict__ Out)
{
  constexpr int BM = 128, BN = 64, BK = 32;
  __shared__ short Ah[BM][BK + 8], Al[BM][BK + 8];
  __shared__ short Bh[BN][BK + 8], Bl[BN][BK + 8];
  const int nT = NCOLS / BN;
  const int bm = blockIdx.x / nT, bn = blockIdx.x % nT;
  const int m0 = bm * BM, n0 = bn * BN;
  const int tid = threadIdx.x, lane = tid & 63, w = tid >> 6;
  const int lo = lane & 15, hi4 = lane >> 4;
  float4_ acc[2][4] = {};

  for (int kb = 0; kb < 512; kb += BK) {
    { // stage A: fp32 -> (hi, lo) bf16
      int r = tid >> 1, kh = (tid & 1) << 4;
      const float* src = X + ((size_t)(m0 + r) << 9) + kb + kh;
      short8 h0, l0, h1, l1;
      #pragma unroll
      for (int u = 0; u < 8; ++u) {
        float xv = src[u];
        short hh = f2bf(xv);
        h0[u] = hh; l0[u] = f2bf(xv - bf2f((unsigned short)hh));
      }
      #pragma unroll
      for (int u = 0; u < 8; ++u) {
        float xv = src[8 + u];
        short hh = f2bf(xv);
        h1[u] = hh; l1[u] = f2bf(xv - bf2f((unsigned short)hh));
      }
      *(short8*)&Ah[r][kh] = h0;  *(short8*)&Ah[r][kh + 8] = h1;
      *(short8*)&Al[r][kh] = l0;  *(short8*)&Al[r][kh + 8] = l1;
    }
    { // stage B
      int cc = tid & 63, kq = tid >> 6;
      *(short8*)&Bh[cc][kq * 8] =
          *(const short8*)(WH + (size_t)(n0 + cc) * 512 + kb + kq * 8);
      *(short8*)&Bl[cc][kq * 8] =
          *(const short8*)(WL + (size_t)(n0 + cc) * 512 + kb + kq * 8);
    }
    __syncthreads();
    short8 bh[4], bl[4], ah[2], al[2];
    #pragma unroll
    for (int sn = 0; sn < 4; ++sn) {
      bh[sn] = *(const short8*)&Bh[sn * 16 + lo][hi4 * 8];
      bl[sn] = *(const short8*)&Bl[sn * 16 + lo][hi4 * 8];
    }
    #pragma unroll
    for (int sm = 0; sm < 2; ++sm) {
      ah[sm] = *(const short8*)&Ah[w * 32 + sm * 16 + lo][hi4 * 8];
      al[sm] = *(const short8*)&Al[w * 32 + sm * 16 + lo][hi4 * 8];
    }
    #pragma unroll
    for (int sm = 0; sm < 2; ++sm)
      #pragma unroll
      for (int sn = 0; sn < 4; ++sn)
        acc[sm][sn] = mfma16(ah[sm], bh[sn], acc[sm][sn]);
    #pragma unroll
    for (int sm = 0; sm < 2; ++sm)
      #pragma unroll
      for (int sn = 0; sn < 4; ++sn)
        acc[sm][sn] = mfma16(al[sm], bh[sn], acc[sm][sn]);
    #pragma unroll
    for (int sm = 0; sm < 2; ++sm)
      #pragma unroll
      for (int sn = 0; sn < 4; ++sn)
        acc[sm][sn] = mfma16(ah[sm], bl[sn], acc[sm][sn]);
    __syncthreads();
  }
  #pragma unroll
  for (int sm = 0; sm < 2; ++sm)
    #pragma unroll
    for (int sn = 0; sn < 4; ++sn)
      #pragma unroll
      for (int i = 0; i < 4; ++i) {
        int row = m0 + w * 32 + sm * 16 + hi4 * 4 + i;
        int col = n0 + sn * 16 + lo;
        Out[(size_t)row * NCOLS + col] = acc[sm][sn][i];
      }
}

// ---------------------------------------------------------------------------
// Persistent scan. Blocks 0..63: phase A (m = mx .* (h@Wmh^T), 16 cols each).
// Blocks 64..319: phase B (z = zx + m@Wh^T + b; gates; h,c update; 4 cols).
// h, m carried as hi/lo bf16 planes; all matvecs 3-term MFMA.
// ---------------------------------------------------------------------------
__global__ __launch_bounds__(64, 1) void scan_kernel(
    const float* __restrict__ mx,    // [8192][1024] fp32
    const float* __restrict__ zx,    // [8192][4096] fp32, permuted cols
    const float* __restrict__ mask,  // [16][512]
    const short* __restrict__ WmhH, const short* __restrict__ WmhL,
    const short* __restrict__ WhH,  const short* __restrict__ WhL,
    const float* __restrict__ bias,  // [4096] raw
    short* __restrict__ hbH, short* __restrict__ hbL,  // [2][16][1024]
    short* __restrict__ mbH, short* __restrict__ mbL,  // [2][16][1024]
    float* __restrict__ out,         // hs | h_fin | c_fin
    unsigned* __restrict__ cnt)      // cnt[0]=cntA, cnt[64]=cntB (zeroed)
{
  const int bid = blockIdx.x;
  const int lane = threadIdx.x;
  const int lo = lane & 15, hi4 = lane >> 4;
  unsigned* cntA = cnt;
  unsigned* cntB = cnt + 64;
  __shared__ float z_s[16][17];

  if (bid < 64) {
    // ---------------- phase-A blocks ----------------
    short8 wAh[32], wAl[32];
    {
      const short* wrH = WmhH + (size_t)(bid * 16 + lo) * 1024 + hi4 * 8;
      const short* wrL = WmhL + (size_t)(bid * 16 + lo) * 1024 + hi4 * 8;
      #pragma unroll
      for (int kc = 0; kc < 32; ++kc) {
        wAh[kc] = *(const short8*)(wrH + kc * 32);
        wAl[kc] = *(const short8*)(wrL + kc * 32);
      }
    }
    for (int t = 0; t < 512; ++t) {
      const int pp = t & 1, pq = pp ^ 1;
      float mxv[4];
      #pragma unroll
      for (int i = 0; i < 4; ++i)
        mxv[i] = mx[((size_t)((hi4 * 4 + i) * 512 + t)) * 1024 + bid * 16 + lo];

      spin_ge(cntB, 256u * (unsigned)t);

      const short* hrH = hbH + pq * 16384 + lo * 1024 + hi4 * 8;
      const short* hrL = hbL + pq * 16384 + lo * 1024 + hi4 * 8;
      float4_ a0 = {0,0,0,0}, a1 = {0,0,0,0}, a2 = {0,0,0,0};
      float4_ a3 = {0,0,0,0}, a4 = {0,0,0,0}, a5 = {0,0,0,0};
      #pragma unroll
      for (int kc = 0; kc < 32; kc += 2) {
        short8 fh0 = *(const short8*)(hrH + (kc + 0) * 32);
        short8 fl0 = *(const short8*)(hrL + (kc + 0) * 32);
        short8 fh1 = *(const short8*)(hrH + (kc + 1) * 32);
        short8 fl1 = *(const short8*)(hrL + (kc + 1) * 32);
        a0 = mfma16(fh0, wAh[kc + 0], a0);
        a1 = mfma16(fl0, wAh[kc + 0], a1);
        a2 = mfma16(fh0, wAl[kc + 0], a2);
        a3 = mfma16(fh1, wAh[kc + 1], a3);
        a4 = mfma16(fl1, wAh[kc + 1], a4);
        a5 = mfma16(fh1, wAl[kc + 1], a5);
      }
      float4_ mres = ((a0 + a1) + (a2 + a3)) + (a4 + a5);
      #pragma unroll
      for (int i = 0; i < 4; ++i) {
        int b = hi4 * 4 + i;
        float mv = mres[i] * mxv[i];
        short mh = f2bf(mv);
        mbH[pp * 16384 + b * 1024 + bid * 16 + lo] = mh;
        mbL[pp * 16384 + b * 1024 + bid * 16 + lo] = f2bf(mv - bf2f((unsigned short)mh));
      }
      release_inc(cntA);
    }
  } else {
    // ---------------- phase-B blocks ----------------
    const int ebid = bid - 64;                 // 0..255
    const int eb = lane >> 2, ejj = lane & 3;  // batch, j-slot
    const int ej = ebid * 4 + ejj;
    float h_st = 0.f, c_st = 0.f;
    float biasr[4];
    #pragma unroll
    for (int g = 0; g < 4; ++g) biasr[g] = bias[g * 1024 + ebid * 4 + ejj];

    short8 wBh[32], wBl[32];
    {
      const int g = lo & 3, jj = lo >> 2;
      const short* wrH = WhH + (size_t)(g * 1024 + ebid * 4 + jj) * 1024 + hi4 * 8;
      const short* wrL = WhL + (size_t)(g * 1024 + ebid * 4 + jj) * 1024 + hi4 * 8;
      #pragma unroll
      for (int kc = 0; kc < 32; ++kc) {
        wBh[kc] = *(const short8*)(wrH + kc * 32);
        wBl[kc] = *(const short8*)(wrL + kc * 32);
      }
    }

    for (int t = 0; t < 512; ++t) {
      const int pp = t & 1;
      float4_ zv = *(const float4_*)(zx + (size_t)(eb * 512 + t) * 4096 + ebid * 16 + ejj * 4);
      float mk = mask[eb * 512 + t];

      spin_ge(cntA, 64u * (unsigned)(t + 1));

      const short* mrH = mbH + pp * 16384 + lo * 1024 + hi4 * 8;
      const short* mrL = mbL + pp * 16384 + lo * 1024 + hi4 * 8;
      float4_ b0 = {0,0,0,0}, b1 = {0,0,0,0}, b2 = {0,0,0,0};
      float4_ b3 = {0,0,0,0}, b4 = {0,0,0,0}, b5 = {0,0,0,0};
      #pragma unroll
      for (int kc = 0; kc < 32; kc += 2) {
        short8 fh0 = *(const short8*)(mrH + (kc + 0) * 32);
        short8 fl0 = *(const short8*)(mrL + (kc + 0) * 32);
        short8 fh1 = *(const short8*)(mrH + (kc + 1) * 32);
        short8 fl1 = *(const short8*)(mrL + (kc + 1) * 32);
        b0 = mfma16(fh0, wBh[kc + 0], b0);
        b1 = mfma16(fl0, wBh[kc + 0], b1);
        b2 = mfma16(fh0, wBl[kc + 0], b2);
        b3 = mfma16(fh1, wBh[kc + 1], b3);
        b4 = mfma16(fl1, wBh[kc + 1], b4);
        b5 = mfma16(fh1, wBl[kc + 1], b5);
      }
      float4_ zres = ((b0 + b1) + (b2 + b3)) + (b4 + b5);
      #pragma unroll
      for (int i = 0; i < 4; ++i) z_s[hi4 * 4 + i][lo] = zres[i];
      __syncthreads();

      float zg[4];
      #pragma unroll
      for (int g = 0; g < 4; ++g)
        zg[g] = z_s[eb][ejj * 4 + g] + zv[g] + biasr[g];
      float ig = sigf(zg[0]), fg = sigf(zg[1]), og = sigf(zg[2]);
      float ug = tanhfast(zg[3]);
      float cn = fg * c_st + ig * ug;
      float hn = og * tanhfast(cn);
      hn = mk * hn + (1.f - mk) * h_st;
      cn = mk * cn + (1.f - mk) * c_st;
      h_st = hn; c_st = cn;

      out[(size_t)(eb * 512 + t) * 1024 + ej] = hn;
      short hh = f2bf(hn);
      hbH[pp * 16384 + eb * 1024 + ej] = hh;
      hbL[pp * 16384 + eb * 1024 + ej] = f2bf(hn - bf2f((unsigned short)hh));
      __syncthreads();
      release_inc(cntB);
    }
    out[HSZ + eb * 1024 + ej] = h_st;
    out[HSZ + 16384 + eb * 1024 + ej] = c_st;
  }
}

// ---------------------------------------------------------------------------
extern "C" void kernel_launch(void* const* d_in, const int* in_sizes, int n_in,
                              void* d_out, int out_size, void* d_ws, size_t ws_size,
                              hipStream_t stream)
{
  (void)in_sizes; (void)n_in; (void)out_size; (void)ws_size;
  const float* x     = (const float*)d_in[0];
  const float* mask  = (const float*)d_in[1];
  const float* wmx_v = (const float*)d_in[2];
  const float* wmx_g = (const float*)d_in[3];
  const float* wmh_v = (const float*)d_in[4];
  const float* wmh_g = (const float*)d_in[5];
  const float* wx_v  = (const float*)d_in[6];
  const float* wx_g  = (const float*)d_in[7];
  const float* wh_v  = (const float*)d_in[8];
  const float* wh_g  = (const float*)d_in[9];
  const float* wh_b  = (const float*)d_in[10];

  char* ws = (char*)d_ws;
  const size_t CNT_OFF  = 0;                       // 4 KB
  const size_t HBH_OFF  = 4096;                    // 64 KB each
  const size_t HBL_OFF  = HBH_OFF + 65536;
  const size_t MBH_OFF  = HBL_OFF + 65536;
  const size_t MBL_OFF  = MBH_OFF + 65536;
  const size_t WMHH_OFF = (size_t)1  << 20;        // 2 MB
  const size_t WMHL_OFF = (size_t)3  << 20;        // 2 MB
  const size_t WHH_OFF  = (size_t)5  << 20;        // 8 MB
  const size_t WHL_OFF  = (size_t)13 << 20;        // 8 MB
  const size_t WMXH_OFF = (size_t)21 << 20;        // 1 MB
  const size_t WMXL_OFF = (size_t)22 << 20;        // 1 MB
  const size_t WXH_OFF  = (size_t)23 << 20;        // 4 MB
  const size_t WXL_OFF  = (size_t)27 << 20;        // 4 MB
  const size_t MX_OFF   = (size_t)32 << 20;        // 32 MB fp32
  const size_t ZX_OFF   = (size_t)64 << 20;        // 128 MB fp32

  unsigned* cnt = (unsigned*)(ws + CNT_OFF);
  short* hbH = (short*)(ws + HBH_OFF);
  short* hbL = (short*)(ws + HBL_OFF);
  short* mbH = (short*)(ws + MBH_OFF);
  short* mbL = (short*)(ws + MBL_OFF);
  short* WmhH = (short*)(ws + WMHH_OFF);
  short* WmhL = (short*)(ws + WMHL_OFF);
  short* WhH  = (short*)(ws + WHH_OFF);
  short* WhL  = (short*)(ws + WHL_OFF);
  short* WmxH = (short*)(ws + WMXH_OFF);
  short* WmxL = (short*)(ws + WMXL_OFF);
  short* WxH  = (short*)(ws + WXH_OFF);
  short* WxL  = (short*)(ws + WXL_OFF);
  float* mx_f = (float*)(ws + MX_OFF);
  float* zx_f = (float*)(ws + ZX_OFF);
  float* out  = (float*)d_out;

  // zero counters + h/m staging (h0 = 0)
  hipMemsetAsync(ws, 0, MBL_OFF + 65536, stream);

  wnorm_kernel<<<1024, 256, 0, stream>>>(wmx_v, wmx_g, WmxH, WmxL, 512, 0);
  wnorm_kernel<<<1024, 256, 0, stream>>>(wmh_v, wmh_g, WmhH, WmhL, 1024, 0);
  wnorm_kernel<<<4096, 256, 0, stream>>>(wx_v,  wx_g,  WxH,  WxL,  512, 1);
  wnorm_kernel<<<4096, 256, 0, stream>>>(wh_v,  wh_g,  WhH,  WhL,  1024, 0);

  gemm_xw<1024><<<64 * 16, 256, 0, stream>>>(x, WmxH, WmxL, mx_f);
  gemm_xw<4096><<<64 * 64, 256, 0, stream>>>(x, WxH,  WxL,  zx_f);

  scan_kernel<<<320, 64, 0, stream>>>(mx_f, zx_f, mask, WmhH, WmhL, WhH, WhL,
                                      wh_b, hbH, hbL, mbH, mbL, out, cnt);
}

// Round 3
// 16830.376 us; speedup vs baseline: 1.3053x; 1.3053x over previous
//
#include <hip/hip_runtime.h>

// ---------------------------------------------------------------------------
// mLSTM persistent-scan kernel for MI355X (gfx950).  B=16,S=512,I=512,H=1024.
// Precision: every bf16 operand split hi+lo (residual ~2^-18), 3-term MFMA.
// Pipeline: wnorm (split weights) -> GEMM mx (fp32) -> GEMM zx (fp32,
// permuted cols) -> persistent scan (16 A-blocks + 64 B-blocks, 256 thr).
// Sync: distributed per-block sequence flags (64B apart) + agent-scope
// write-through data stores; consumers acquire-fence + normal b128 loads.
// ---------------------------------------------------------------------------

typedef __attribute__((ext_vector_type(8))) short   short8;
typedef __attribute__((ext_vector_type(4))) float   float4_;

#define HSZ (16 * 512 * 1024)

__device__ __forceinline__ short f2bf(float x) {
  unsigned u = __float_as_uint(x);
  u += 0x7FFFu + ((u >> 16) & 1u);           // RNE
  return (short)(u >> 16);
}
__device__ __forceinline__ float bf2f(unsigned short s) {
  return __uint_as_float(((unsigned)s) << 16);
}
__device__ __forceinline__ float sigf(float x) { return 1.f / (1.f + __expf(-x)); }
__device__ __forceinline__ float tanhfast(float x) { return 2.f / (1.f + __expf(-2.f * x)) - 1.f; }

__device__ __forceinline__ float4_ mfma16(short8 a, short8 b, float4_ c) {
  return __builtin_amdgcn_mfma_f32_16x16x32_bf16(a, b, c, 0, 0, 0);
}

__device__ __forceinline__ unsigned ld_flag(const unsigned* p) {
  return __hip_atomic_load(p, __ATOMIC_RELAXED, __HIP_MEMORY_SCOPE_AGENT);
}
__device__ __forceinline__ void st_agent(unsigned* p, unsigned v) {
  __hip_atomic_store(p, v, __ATOMIC_RELAXED, __HIP_MEMORY_SCOPE_AGENT);
}

// ---------------------------------------------------------------------------
// Weight-norm: W = v*g/||v||, emitted as hi/lo bf16 planes.
// permute!=0 (Wx): out row r <- src row (r&3)*1024 + (r>>4)*4 + ((r>>2)&3).
// ---------------------------------------------------------------------------
__global__ __launch_bounds__(256) void wnorm_kernel(
    const float* __restrict__ v, const float* __restrict__ g,
    short* __restrict__ outH, short* __restrict__ outL, int cols, int permute)
{
  int r = blockIdx.x, tid = threadIdx.x;
  int src = r;
  if (permute) {
    int bid = r >> 4, jj = (r >> 2) & 3, gg = r & 3;
    src = gg * 1024 + bid * 4 + jj;
  }
  const float* row = v + (size_t)src * cols;
  float s = 0.f;
  for (int c = tid; c < cols; c += 256) { float x = row[c]; s += x * x; }
  #pragma unroll
  for (int off = 32; off; off >>= 1) s += __shfl_down(s, off);
  __shared__ float red[4];
  if ((tid & 63) == 0) red[tid >> 6] = s;
  __syncthreads();
  float tot = red[0] + red[1] + red[2] + red[3];
  float scale = g[src] / sqrtf(tot);
  for (int c = tid; c < cols; c += 256) {
    float wv = row[c] * scale;
    short hh = f2bf(wv);
    outH[(size_t)r * cols + c] = hh;
    outL[(size_t)r * cols + c] = f2bf(wv - bf2f((unsigned short)hh));
  }
}

// ---------------------------------------------------------------------------
// GEMM: Out[8192][NCOLS] (fp32) = X[8192][512] @ W[NCOLS][512]^T, W pre-split.
// x split hi/lo on the fly; 3-term MFMA. BM=128 BN=64 BK=32, 4 waves.
// ---------------------------------------------------------------------------
template <int NCOLS>
__global__ __launch_bounds__(256) void gemm_xw(
    const float* __restrict__ X,
    const short* __restrict__ WH, const short* __restrict__ WL,
    float* __restrict__ Out)
{
  constexpr int BM = 128, BN = 64, BK = 32;
  __shared__ short Ah[BM][BK + 8], Al[BM][BK + 8];
  __shared__ short Bh[BN][BK + 8], Bl[BN][BK + 8];
  const int nT = NCOLS / BN;
  const int bm = blockIdx.x / nT, bn = blockIdx.x % nT;
  const int m0 = bm * BM, n0 = bn * BN;
  const int tid = threadIdx.x, lane = tid & 63, w = tid >> 6;
  const int lo = lane & 15, hi4 = lane >> 4;
  float4_ acc[2][4] = {};

  for (int kb = 0; kb < 512; kb += BK) {
    { // stage A: fp32 -> (hi, lo) bf16
      int r = tid >> 1, kh = (tid & 1) << 4;
      const float* src = X + ((size_t)(m0 + r) << 9) + kb + kh;
      short8 h0, l0, h1, l1;
      #pragma unroll
      for (int u = 0; u < 8; ++u) {
        float xv = src[u];
        short hh = f2bf(xv);
        h0[u] = hh; l0[u] = f2bf(xv - bf2f((unsigned short)hh));
      }
      #pragma unroll
      for (int u = 0; u < 8; ++u) {
        float xv = src[8 + u];
        short hh = f2bf(xv);
        h1[u] = hh; l1[u] = f2bf(xv - bf2f((unsigned short)hh));
      }
      *(short8*)&Ah[r][kh] = h0;  *(short8*)&Ah[r][kh + 8] = h1;
      *(short8*)&Al[r][kh] = l0;  *(short8*)&Al[r][kh + 8] = l1;
    }
    { // stage B
      int cc = tid & 63, kq = tid >> 6;
      *(short8*)&Bh[cc][kq * 8] =
          *(const short8*)(WH + (size_t)(n0 + cc) * 512 + kb + kq * 8);
      *(short8*)&Bl[cc][kq * 8] =
          *(const short8*)(WL + (size_t)(n0 + cc) * 512 + kb + kq * 8);
    }
    __syncthreads();
    short8 bh[4], bl[4], ah[2], al[2];
    #pragma unroll
    for (int sn = 0; sn < 4; ++sn) {
      bh[sn] = *(const short8*)&Bh[sn * 16 + lo][hi4 * 8];
      bl[sn] = *(const short8*)&Bl[sn * 16 + lo][hi4 * 8];
    }
    #pragma unroll
    for (int sm = 0; sm < 2; ++sm) {
      ah[sm] = *(const short8*)&Ah[w * 32 + sm * 16 + lo][hi4 * 8];
      al[sm] = *(const short8*)&Al[w * 32 + sm * 16 + lo][hi4 * 8];
    }
    #pragma unroll
    for (int sm = 0; sm < 2; ++sm)
      #pragma unroll
      for (int sn = 0; sn < 4; ++sn)
        acc[sm][sn] = mfma16(ah[sm], bh[sn], acc[sm][sn]);
    #pragma unroll
    for (int sm = 0; sm < 2; ++sm)
      #pragma unroll
      for (int sn = 0; sn < 4; ++sn)
        acc[sm][sn] = mfma16(al[sm], bh[sn], acc[sm][sn]);
    #pragma unroll
    for (int sm = 0; sm < 2; ++sm)
      #pragma unroll
      for (int sn = 0; sn < 4; ++sn)
        acc[sm][sn] = mfma16(ah[sm], bl[sn], acc[sm][sn]);
    __syncthreads();
  }
  #pragma unroll
  for (int sm = 0; sm < 2; ++sm)
    #pragma unroll
    for (int sn = 0; sn < 4; ++sn)
      #pragma unroll
      for (int i = 0; i < 4; ++i) {
        int row = m0 + w * 32 + sm * 16 + hi4 * 4 + i;
        int col = n0 + sn * 16 + lo;
        Out[(size_t)row * NCOLS + col] = acc[sm][sn][i];
      }
}

// ---------------------------------------------------------------------------
// Persistent scan. Blocks 0..15 (4 waves each): phase A, wave handles m-slice
// bid = blk*4+w (16 cols). Blocks 16..79: phase B, wave handles ebid =
// (blk-16)*4+w (4 h-cols x 4 gates).
// Protocol per step:
//   producer: packed sc1 (agent) 4B data stores -> s_waitcnt vmcnt(0)
//             -> flag[blk] = t+1 (agent relaxed, own 64B line)
//   consumer: wave0 lane-parallel polls flags -> __syncthreads
//             -> fence(acquire, agent) per wave -> normal b128 loads
// ---------------------------------------------------------------------------
__global__ __launch_bounds__(256, 1) void scan_kernel(
    const float* __restrict__ mx,    // [16*512][1024] fp32
    const float* __restrict__ zx,    // [16*512][4096] fp32, permuted cols
    const float* __restrict__ mask,  // [16][512]
    const short* __restrict__ WmhH, const short* __restrict__ WmhL,
    const short* __restrict__ WhH,  const short* __restrict__ WhL,
    const float* __restrict__ bias,  // [4096] raw
    short* __restrict__ hbH, short* __restrict__ hbL,  // [2][16][1024]
    short* __restrict__ mbH, short* __restrict__ mbL,  // [2][16][1024]
    float* __restrict__ out,         // hs | h_fin | c_fin
    unsigned* __restrict__ flagA,    // 16 flags, 16-uint stride (zeroed)
    unsigned* __restrict__ flagB)    // 64 flags, 16-uint stride (zeroed)
{
  const int blk = blockIdx.x;
  const int tid = threadIdx.x;
  const int w = tid >> 6, lane = tid & 63;
  const int lo = lane & 15, hi4 = lane >> 4;

  if (blk < 16) {
    // ---------------- phase-A blocks ----------------
    const int bid = blk * 4 + w;               // 0..63, m cols [16*bid,+16)
    short8 wAh[32], wAl[32];
    {
      const short* wrH = WmhH + (size_t)(bid * 16 + lo) * 1024 + hi4 * 8;
      const short* wrL = WmhL + (size_t)(bid * 16 + lo) * 1024 + hi4 * 8;
      #pragma unroll
      for (int kc = 0; kc < 32; ++kc) {
        wAh[kc] = *(const short8*)(wrH + kc * 32);
        wAl[kc] = *(const short8*)(wrL + kc * 32);
      }
    }
    for (int t = 0; t < 512; ++t) {
      const int pp = t & 1, pq = pp ^ 1;
      float mxv[4];
      #pragma unroll
      for (int i = 0; i < 4; ++i)
        mxv[i] = mx[((size_t)((hi4 * 4 + i) * 512 + t)) * 1024 + bid * 16 + lo];

      if (w == 0) {                       // poll: all 64 B-flags >= t
        const unsigned tgt = (unsigned)t;
        for (;;) {
          unsigned v = ld_flag(flagB + lane * 16);
          if (__all((int)(v >= tgt))) break;
          __builtin_amdgcn_s_sleep(1);
        }
      }
      __syncthreads();
      __builtin_amdgcn_fence(__ATOMIC_ACQUIRE, "agent");

      const short* hrH = hbH + pq * 16384 + lo * 1024 + hi4 * 8;
      const short* hrL = hbL + pq * 16384 + lo * 1024 + hi4 * 8;
      float4_ a0 = {0,0,0,0}, a1 = {0,0,0,0}, a2 = {0,0,0,0};
      float4_ a3 = {0,0,0,0}, a4 = {0,0,0,0}, a5 = {0,0,0,0};
      #pragma unroll
      for (int kc = 0; kc < 32; kc += 2) {
        short8 fh0 = *(const short8*)(hrH + (kc + 0) * 32);
        short8 fl0 = *(const short8*)(hrL + (kc + 0) * 32);
        short8 fh1 = *(const short8*)(hrH + (kc + 1) * 32);
        short8 fl1 = *(const short8*)(hrL + (kc + 1) * 32);
        a0 = mfma16(fh0, wAh[kc + 0], a0);
        a1 = mfma16(fl0, wAh[kc + 0], a1);
        a2 = mfma16(fh0, wAl[kc + 0], a2);
        a3 = mfma16(fh1, wAh[kc + 1], a3);
        a4 = mfma16(fl1, wAh[kc + 1], a4);
        a5 = mfma16(fh1, wAl[kc + 1], a5);
      }
      float4_ mres = ((a0 + a1) + (a2 + a3)) + (a4 + a5);
      #pragma unroll
      for (int i = 0; i < 4; ++i) {
        const int b = hi4 * 4 + i;
        float mv = mres[i] * mxv[i];
        short mh = f2bf(mv);
        short ml = f2bf(mv - bf2f((unsigned short)mh));
        unsigned hv = (unsigned short)mh, lv2 = (unsigned short)ml;
        unsigned hp = hv  | (((unsigned)__shfl_xor((int)hv, 1)) << 16);
        unsigned lp = lv2 | (((unsigned)__shfl_xor((int)lv2, 1)) << 16);
        if ((lo & 1) == 0) {
          st_agent((unsigned*)(mbH + pp * 16384 + b * 1024 + bid * 16 + lo), hp);
          st_agent((unsigned*)(mbL + pp * 16384 + b * 1024 + bid * 16 + lo), lp);
        }
      }
      asm volatile("s_waitcnt vmcnt(0)" ::: "memory");
      __syncthreads();
      if (tid == 0) st_agent(flagA + blk * 16, (unsigned)(t + 1));
    }
  } else {
    // ---------------- phase-B blocks ----------------
    const int ebid = (blk - 16) * 4 + w;       // 0..255
    const int eb = lane >> 2, ejj = lane & 3;  // batch, j-slot
    const int ej = ebid * 4 + ejj;
    float h_st = 0.f, c_st = 0.f;
    float biasr[4];
    #pragma unroll
    for (int g = 0; g < 4; ++g) biasr[g] = bias[g * 1024 + ebid * 4 + ejj];

    short8 wBh[32], wBl[32];
    {
      const int g = lo & 3, jj = lo >> 2;
      const short* wrH = WhH + (size_t)(g * 1024 + ebid * 4 + jj) * 1024 + hi4 * 8;
      const short* wrL = WhL + (size_t)(g * 1024 + ebid * 4 + jj) * 1024 + hi4 * 8;
      #pragma unroll
      for (int kc = 0; kc < 32; ++kc) {
        wBh[kc] = *(const short8*)(wrH + kc * 32);
        wBl[kc] = *(const short8*)(wrL + kc * 32);
      }
    }
    __shared__ float z_s[4][16][17];

    for (int t = 0; t < 512; ++t) {
      const int pp = t & 1;
      float4_ zv = *(const float4_*)(zx + (size_t)(eb * 512 + t) * 4096 + ebid * 16 + ejj * 4);
      float mk = mask[eb * 512 + t];

      if (w == 0) {                      // poll: all 16 A-flags >= t+1
        const unsigned tgt = (unsigned)(t + 1);
        for (;;) {
          unsigned v = 0xFFFFFFFFu;
          if (lane < 16) v = ld_flag(flagA + lane * 16);
          if (__all((int)(v >= tgt))) break;
          __builtin_amdgcn_s_sleep(1);
        }
      }
      __syncthreads();
      __builtin_amdgcn_fence(__ATOMIC_ACQUIRE, "agent");

      const short* mrH = mbH + pp * 16384 + lo * 1024 + hi4 * 8;
      const short* mrL = mbL + pp * 16384 + lo * 1024 + hi4 * 8;
      float4_ b0 = {0,0,0,0}, b1 = {0,0,0,0}, b2 = {0,0,0,0};
      float4_ b3 = {0,0,0,0}, b4 = {0,0,0,0}, b5 = {0,0,0,0};
      #pragma unroll
      for (int kc = 0; kc < 32; kc += 2) {
        short8 fh0 = *(const short8*)(mrH + (kc + 0) * 32);
        short8 fl0 = *(const short8*)(mrL + (kc + 0) * 32);
        short8 fh1 = *(const short8*)(mrH + (kc + 1) * 32);
        short8 fl1 = *(const short8*)(mrL + (kc + 1) * 32);
        b0 = mfma16(fh0, wBh[kc + 0], b0);
        b1 = mfma16(fl0, wBh[kc + 0], b1);
        b2 = mfma16(fh0, wBl[kc + 0], b2);
        b3 = mfma16(fh1, wBh[kc + 1], b3);
        b4 = mfma16(fl1, wBh[kc + 1], b4);
        b5 = mfma16(fh1, wBl[kc + 1], b5);
      }
      float4_ zres = ((b0 + b1) + (b2 + b3)) + (b4 + b5);
      #pragma unroll
      for (int i = 0; i < 4; ++i) z_s[w][hi4 * 4 + i][lo] = zres[i];
      asm volatile("s_waitcnt lgkmcnt(0)" ::: "memory");

      float zg[4];
      #pragma unroll
      for (int g = 0; g < 4; ++g)
        zg[g] = z_s[w][eb][ejj * 4 + g] + zv[g] + biasr[g];
      float ig = sigf(zg[0]), fg = sigf(zg[1]), og = sigf(zg[2]);
      float ug = tanhfast(zg[3]);
      float cn = fg * c_st + ig * ug;
      float hn = og * tanhfast(cn);
      hn = mk * hn + (1.f - mk) * h_st;
      cn = mk * cn + (1.f - mk) * c_st;
      h_st = hn; c_st = cn;

      out[(size_t)(eb * 512 + t) * 1024 + ej] = hn;   // normal store
      short hh = f2bf(hn);
      short hl = f2bf(hn - bf2f((unsigned short)hh));
      unsigned hv = (unsigned short)hh, lv2 = (unsigned short)hl;
      unsigned hp = hv  | (((unsigned)__shfl_xor((int)hv, 1)) << 16);
      unsigned lp = lv2 | (((unsigned)__shfl_xor((int)lv2, 1)) << 16);
      if ((ejj & 1) == 0) {
        st_agent((unsigned*)(hbH + pp * 16384 + eb * 1024 + ej), hp);
        st_agent((unsigned*)(hbL + pp * 16384 + eb * 1024 + ej), lp);
      }
      asm volatile("s_waitcnt vmcnt(0)" ::: "memory");
      __syncthreads();
      if (tid == 0) st_agent(flagB + (blk - 16) * 16, (unsigned)(t + 1));
    }
    out[HSZ + eb * 1024 + ej] = h_st;
    out[HSZ + 16384 + eb * 1024 + ej] = c_st;
  }
}

// ---------------------------------------------------------------------------
extern "C" void kernel_launch(void* const* d_in, const int* in_sizes, int n_in,
                              void* d_out, int out_size, void* d_ws, size_t ws_size,
                              hipStream_t stream)
{
  (void)in_sizes; (void)n_in; (void)out_size; (void)ws_size;
  const float* x     = (const float*)d_in[0];
  const float* mask  = (const float*)d_in[1];
  const float* wmx_v = (const float*)d_in[2];
  const float* wmx_g = (const float*)d_in[3];
  const float* wmh_v = (const float*)d_in[4];
  const float* wmh_g = (const float*)d_in[5];
  const float* wx_v  = (const float*)d_in[6];
  const float* wx_g  = (const float*)d_in[7];
  const float* wh_v  = (const float*)d_in[8];
  const float* wh_g  = (const float*)d_in[9];
  const float* wh_b  = (const float*)d_in[10];

  char* ws = (char*)d_ws;
  const size_t FLAGA_OFF = 0;                      // 16 x 64B = 1 KB
  const size_t FLAGB_OFF = 1024;                   // 64 x 64B = 4 KB
  const size_t HBH_OFF   = 8192;                   // 64 KB each
  const size_t HBL_OFF   = HBH_OFF + 65536;
  const size_t MBH_OFF   = HBL_OFF + 65536;
  const size_t MBL_OFF   = MBH_OFF + 65536;
  const size_t WMHH_OFF  = (size_t)1  << 20;       // 2 MB
  const size_t WMHL_OFF  = (size_t)3  << 20;       // 2 MB
  const size_t WHH_OFF   = (size_t)5  << 20;       // 8 MB
  const size_t WHL_OFF   = (size_t)13 << 20;       // 8 MB
  const size_t WMXH_OFF  = (size_t)21 << 20;       // 1 MB
  const size_t WMXL_OFF  = (size_t)22 << 20;       // 1 MB
  const size_t WXH_OFF   = (size_t)23 << 20;       // 4 MB
  const size_t WXL_OFF   = (size_t)27 << 20;       // 4 MB
  const size_t MX_OFF    = (size_t)32 << 20;       // 32 MB fp32
  const size_t ZX_OFF    = (size_t)64 << 20;       // 128 MB fp32

  unsigned* flagA = (unsigned*)(ws + FLAGA_OFF);
  unsigned* flagB = (unsigned*)(ws + FLAGB_OFF);
  short* hbH = (short*)(ws + HBH_OFF);
  short* hbL = (short*)(ws + HBL_OFF);
  short* mbH = (short*)(ws + MBH_OFF);
  short* mbL = (short*)(ws + MBL_OFF);
  short* WmhH = (short*)(ws + WMHH_OFF);
  short* WmhL = (short*)(ws + WMHL_OFF);
  short* WhH  = (short*)(ws + WHH_OFF);
  short* WhL  = (short*)(ws + WHL_OFF);
  short* WmxH = (short*)(ws + WMXH_OFF);
  short* WmxL = (short*)(ws + WMXL_OFF);
  short* WxH  = (short*)(ws + WXH_OFF);
  short* WxL  = (short*)(ws + WXL_OFF);
  float* mx_f = (float*)(ws + MX_OFF);
  float* zx_f = (float*)(ws + ZX_OFF);
  float* out  = (float*)d_out;

  // zero flags + h/m staging (h0 = 0)
  hipMemsetAsync(ws, 0, MBL_OFF + 65536, stream);

  wnorm_kernel<<<1024, 256, 0, stream>>>(wmx_v, wmx_g, WmxH, WmxL, 512, 0);
  wnorm_kernel<<<1024, 256, 0, stream>>>(wmh_v, wmh_g, WmhH, WmhL, 1024, 0);
  wnorm_kernel<<<4096, 256, 0, stream>>>(wx_v,  wx_g,  WxH,  WxL,  512, 1);
  wnorm_kernel<<<4096, 256, 0, stream>>>(wh_v,  wh_g,  WhH,  WhL,  1024, 0);

  gemm_xw<1024><<<64 * 16, 256, 0, stream>>>(x, WmxH, WmxL, mx_f);
  gemm_xw<4096><<<64 * 64, 256, 0, stream>>>(x, WxH,  WxL,  zx_f);

  scan_kernel<<<80, 256, 0, stream>>>(mx_f, zx_f, mask, WmhH, WmhL, WhH, WhL,
                                      wh_b, hbH, hbL, mbH, mbL, out, flagA, flagB);
}

// Round 5
// 16345.374 us; speedup vs baseline: 1.3440x; 1.0297x over previous
//
#include <hip/hip_runtime.h>

// ---------------------------------------------------------------------------
// mLSTM persistent-scan kernel for MI355X (gfx950).  B=16,S=512,I=512,H=1024.
// Precision: every bf16 operand split hi+lo (residual ~2^-18), 3-term MFMA.
// Pipeline: wnorm (split weights) -> GEMM mx (fp32) -> GEMM zx (fp32,
// permuted cols) -> persistent scan (16 A-blocks + 64 B-blocks, 256 thr).
// Round-5 changes:
//  * inline-asm MFMA hazard fix: s_nop 1 inside each MFMA (VALU->Src hazard),
//    s_nop 7 x3 dependency fence before reading accumulators (D->VALU hazard).
//    Round-4's corruption came from missing manual wait-states (compiler only
//    inserts them for builtins).
//  * per-step acquire fence (buffer_inv: full L1+L2 invalidate!) replaced by
//    coherent 8B agent-scope atomic loads of the h/m staging (read straight
//    from MALL, caches stay warm). Producer protocol unchanged from the
//    passing round 3.
// ---------------------------------------------------------------------------

typedef __attribute__((ext_vector_type(8))) short   short8;
typedef __attribute__((ext_vector_type(4))) float   float4_;

#define HSZ (16 * 512 * 1024)

__device__ __forceinline__ short f2bf(float x) {
  unsigned u = __float_as_uint(x);
  u += 0x7FFFu + ((u >> 16) & 1u);           // RNE
  return (short)(u >> 16);
}
__device__ __forceinline__ float bf2f(unsigned short s) {
  return __uint_as_float(((unsigned)s) << 16);
}
__device__ __forceinline__ float sigf(float x) { return 1.f / (1.f + __expf(-x)); }
__device__ __forceinline__ float tanhfast(float x) { return 2.f / (1.f + __expf(-2.f * x)) - 1.f; }

__device__ __forceinline__ float4_ mfma16(short8 a, short8 b, float4_ c) {
  return __builtin_amdgcn_mfma_f32_16x16x32_bf16(a, b, c, 0, 0, 0);
}
// MFMA with B operand pinned to AGPRs. Leading s_nop 1 covers the
// VALU-write -> MFMA-read (SrcA/B/C) hazard that the compiler does not
// manage for inline asm.
__device__ __forceinline__ void mfma_aw(float4_& acc, short8 a, const short8& b_agpr) {
  asm("s_nop 1\n\tv_mfma_f32_16x16x32_bf16 %0, %1, %2, %0"
      : "+v"(acc) : "v"(a), "a"(b_agpr));
}
// Dependency-carrying fence: guarantees >=24 wait states between the last
// MFMA writing these accs and any VALU read of them.
#define ACC_FENCE(x0,x1,x2,x3,x4,x5)                                   \
  asm volatile("s_nop 7\n\ts_nop 7\n\ts_nop 7"                         \
    : "+v"(x0), "+v"(x1), "+v"(x2), "+v"(x3), "+v"(x4), "+v"(x5))

__device__ __forceinline__ unsigned ld_flag(const unsigned* p) {
  return __hip_atomic_load(p, __ATOMIC_RELAXED, __HIP_MEMORY_SCOPE_AGENT);
}
__device__ __forceinline__ void st_agent(unsigned* p, unsigned v) {
  __hip_atomic_store(p, v, __ATOMIC_RELAXED, __HIP_MEMORY_SCOPE_AGENT);
}
// Coherent 16B staging read: two 8B agent-scope relaxed atomic loads
// (global_load_dwordx2 sc1 -> served from MALL; no cache invalidation).
__device__ __forceinline__ short8 ld16_coh(const short* p) {
  const unsigned long long* q = (const unsigned long long*)p;
  unsigned long long x0 = __hip_atomic_load(q,     __ATOMIC_RELAXED, __HIP_MEMORY_SCOPE_AGENT);
  unsigned long long x1 = __hip_atomic_load(q + 1, __ATOMIC_RELAXED, __HIP_MEMORY_SCOPE_AGENT);
  union { short8 s; unsigned long long u[2]; } r;
  r.u[0] = x0; r.u[1] = x1;
  return r.s;
}

// ---------------------------------------------------------------------------
// Weight-norm: W = v*g/||v||, emitted as hi/lo bf16 planes.
// permute!=0 (Wx): out row r <- src row (r&3)*1024 + (r>>4)*4 + ((r>>2)&3).
// ---------------------------------------------------------------------------
__global__ __launch_bounds__(256) void wnorm_kernel(
    const float* __restrict__ v, const float* __restrict__ g,
    short* __restrict__ outH, short* __restrict__ outL, int cols, int permute)
{
  int r = blockIdx.x, tid = threadIdx.x;
  int src = r;
  if (permute) {
    int bid = r >> 4, jj = (r >> 2) & 3, gg = r & 3;
    src = gg * 1024 + bid * 4 + jj;
  }
  const float* row = v + (size_t)src * cols;
  float s = 0.f;
  for (int c = tid; c < cols; c += 256) { float x = row[c]; s += x * x; }
  #pragma unroll
  for (int off = 32; off; off >>= 1) s += __shfl_down(s, off);
  __shared__ float red[4];
  if ((tid & 63) == 0) red[tid >> 6] = s;
  __syncthreads();
  float tot = red[0] + red[1] + red[2] + red[3];
  float scale = g[src] / sqrtf(tot);
  for (int c = tid; c < cols; c += 256) {
    float wv = row[c] * scale;
    short hh = f2bf(wv);
    outH[(size_t)r * cols + c] = hh;
    outL[(size_t)r * cols + c] = f2bf(wv - bf2f((unsigned short)hh));
  }
}

// ---------------------------------------------------------------------------
// GEMM: Out[8192][NCOLS] (fp32) = X[8192][512] @ W[NCOLS][512]^T, W pre-split.
// x split hi/lo on the fly; 3-term MFMA (builtins). BM=128 BN=64 BK=32.
// ---------------------------------------------------------------------------
template <int NCOLS>
__global__ __launch_bounds__(256) void gemm_xw(
    const float* __restrict__ X,
    const short* __restrict__ WH, const short* __restrict__ WL,
    float* __restrict__ Out)
{
  constexpr int BM = 128, BN = 64, BK = 32;
  __shared__ short Ah[BM][BK + 8], Al[BM][BK + 8];
  __shared__ short Bh[BN][BK + 8], Bl[BN][BK + 8];
  const int nT = NCOLS / BN;
  const int bm = blockIdx.x / nT, bn = blockIdx.x % nT;
  const int m0 = bm * BM, n0 = bn * BN;
  const int tid = threadIdx.x, lane = tid & 63, w = tid >> 6;
  const int lo = lane & 15, hi4 = lane >> 4;
  float4_ acc[2][4] = {};

  for (int kb = 0; kb < 512; kb += BK) {
    { // stage A: fp32 -> (hi, lo) bf16
      int r = tid >> 1, kh = (tid & 1) << 4;
      const float* src = X + ((size_t)(m0 + r) << 9) + kb + kh;
      short8 h0, l0, h1, l1;
      #pragma unroll
      for (int u = 0; u < 8; ++u) {
        float xv = src[u];
        short hh = f2bf(xv);
        h0[u] = hh; l0[u] = f2bf(xv - bf2f((unsigned short)hh));
      }
      #pragma unroll
      for (int u = 0; u < 8; ++u) {
        float xv = src[8 + u];
        short hh = f2bf(xv);
        h1[u] = hh; l1[u] = f2bf(xv - bf2f((unsigned short)hh));
      }
      *(short8*)&Ah[r][kh] = h0;  *(short8*)&Ah[r][kh + 8] = h1;
      *(short8*)&Al[r][kh] = l0;  *(short8*)&Al[r][kh + 8] = l1;
    }
    { // stage B
      int cc = tid & 63, kq = tid >> 6;
      *(short8*)&Bh[cc][kq * 8] =
          *(const short8*)(WH + (size_t)(n0 + cc) * 512 + kb + kq * 8);
      *(short8*)&Bl[cc][kq * 8] =
          *(const short8*)(WL + (size_t)(n0 + cc) * 512 + kb + kq * 8);
    }
    __syncthreads();
    short8 bh[4], bl[4], ah[2], al[2];
    #pragma unroll
    for (int sn = 0; sn < 4; ++sn) {
      bh[sn] = *(const short8*)&Bh[sn * 16 + lo][hi4 * 8];
      bl[sn] = *(const short8*)&Bl[sn * 16 + lo][hi4 * 8];
    }
    #pragma unroll
    for (int sm = 0; sm < 2; ++sm) {
      ah[sm] = *(const short8*)&Ah[w * 32 + sm * 16 + lo][hi4 * 8];
      al[sm] = *(const short8*)&Al[w * 32 + sm * 16 + lo][hi4 * 8];
    }
    #pragma unroll
    for (int sm = 0; sm < 2; ++sm)
      #pragma unroll
      for (int sn = 0; sn < 4; ++sn)
        acc[sm][sn] = mfma16(ah[sm], bh[sn], acc[sm][sn]);
    #pragma unroll
    for (int sm = 0; sm < 2; ++sm)
      #pragma unroll
      for (int sn = 0; sn < 4; ++sn)
        acc[sm][sn] = mfma16(al[sm], bh[sn], acc[sm][sn]);
    #pragma unroll
    for (int sm = 0; sm < 2; ++sm)
      #pragma unroll
      for (int sn = 0; sn < 4; ++sn)
        acc[sm][sn] = mfma16(ah[sm], bl[sn], acc[sm][sn]);
    __syncthreads();
  }
  #pragma unroll
  for (int sm = 0; sm < 2; ++sm)
    #pragma unroll
    for (int sn = 0; sn < 4; ++sn)
      #pragma unroll
      for (int i = 0; i < 4; ++i) {
        int row = m0 + w * 32 + sm * 16 + hi4 * 4 + i;
        int col = n0 + sn * 16 + lo;
        Out[(size_t)row * NCOLS + col] = acc[sm][sn][i];
      }
}

// ---------------------------------------------------------------------------
// Persistent scan. Blocks 0..15 (4 waves each): phase A, wave handles m-slice
// bid = blk*4+w (16 cols). Blocks 16..79: phase B, wave handles ebid =
// (blk-16)*4+w (4 h-cols x 4 gates). Weights in AGPRs (256/wave).
// ---------------------------------------------------------------------------
__global__ __launch_bounds__(256, 1) void scan_kernel(
    const float* __restrict__ mx,    // [16*512][1024] fp32
    const float* __restrict__ zx,    // [16*512][4096] fp32, permuted cols
    const float* __restrict__ mask,  // [16][512]
    const short* __restrict__ WmhH, const short* __restrict__ WmhL,
    const short* __restrict__ WhH,  const short* __restrict__ WhL,
    const float* __restrict__ bias,  // [4096] raw
    short* __restrict__ hbH, short* __restrict__ hbL,  // [2][16][1024]
    short* __restrict__ mbH, short* __restrict__ mbL,  // [2][16][1024]
    float* __restrict__ out,         // hs | h_fin | c_fin
    unsigned* __restrict__ flagA,    // 16 flags, 16-uint stride (zeroed)
    unsigned* __restrict__ flagB)    // 64 flags, 16-uint stride (zeroed)
{
  const int blk = blockIdx.x;
  const int tid = threadIdx.x;
  const int w = tid >> 6, lane = tid & 63;
  const int lo = lane & 15, hi4 = lane >> 4;

  if (blk < 16) {
    // ---------------- phase-A blocks ----------------
    const int bid = blk * 4 + w;               // 0..63, m cols [16*bid,+16)
    short8 wAh[32], wAl[32];                   // -> AGPRs (uses are "a" only)
    {
      const short* wrH = WmhH + (size_t)(bid * 16 + lo) * 1024 + hi4 * 8;
      const short* wrL = WmhL + (size_t)(bid * 16 + lo) * 1024 + hi4 * 8;
      #pragma unroll
      for (int kc = 0; kc < 32; ++kc) {
        wAh[kc] = *(const short8*)(wrH + kc * 32);
        wAl[kc] = *(const short8*)(wrL + kc * 32);
      }
    }
    for (int t = 0; t < 512; ++t) {
      const int pp = t & 1, pq = pp ^ 1;
      float mxv[4];
      #pragma unroll
      for (int i = 0; i < 4; ++i)
        mxv[i] = mx[((size_t)((hi4 * 4 + i) * 512 + t)) * 1024 + bid * 16 + lo];

      if (w == 0) {                       // poll: all 64 B-flags >= t
        const unsigned tgt = (unsigned)t;
        for (;;) {
          unsigned v = ld_flag(flagB + lane * 16);
          if (__all((int)(v >= tgt))) break;
          __builtin_amdgcn_s_sleep(1);
        }
      }
      __syncthreads();
      __builtin_amdgcn_sched_barrier(0);

      const short* hrH = hbH + pq * 16384 + lo * 1024 + hi4 * 8;
      const short* hrL = hbL + pq * 16384 + lo * 1024 + hi4 * 8;
      float4_ a0 = {0,0,0,0}, a1 = {0,0,0,0}, a2 = {0,0,0,0};
      float4_ a3 = {0,0,0,0}, a4 = {0,0,0,0}, a5 = {0,0,0,0};
      #pragma unroll
      for (int kc = 0; kc < 32; kc += 2) {
        short8 fh0 = ld16_coh(hrH + (kc + 0) * 32);
        short8 fl0 = ld16_coh(hrL + (kc + 0) * 32);
        short8 fh1 = ld16_coh(hrH + (kc + 1) * 32);
        short8 fl1 = ld16_coh(hrL + (kc + 1) * 32);
        mfma_aw(a0, fh0, wAh[kc + 0]);
        mfma_aw(a1, fl0, wAh[kc + 0]);
        mfma_aw(a2, fh0, wAl[kc + 0]);
        mfma_aw(a3, fh1, wAh[kc + 1]);
        mfma_aw(a4, fl1, wAh[kc + 1]);
        mfma_aw(a5, fh1, wAl[kc + 1]);
      }
      ACC_FENCE(a0, a1, a2, a3, a4, a5);
      float4_ mres = ((a0 + a1) + (a2 + a3)) + (a4 + a5);
      #pragma unroll
      for (int i = 0; i < 4; ++i) {
        const int b = hi4 * 4 + i;
        float mv = mres[i] * mxv[i];
        short mh = f2bf(mv);
        short ml = f2bf(mv - bf2f((unsigned short)mh));
        unsigned hv = (unsigned short)mh, lv2 = (unsigned short)ml;
        unsigned hp = hv  | (((unsigned)__shfl_xor((int)hv, 1)) << 16);
        unsigned lp = lv2 | (((unsigned)__shfl_xor((int)lv2, 1)) << 16);
        if ((lo & 1) == 0) {
          st_agent((unsigned*)(mbH + pp * 16384 + b * 1024 + bid * 16 + lo), hp);
          st_agent((unsigned*)(mbL + pp * 16384 + b * 1024 + bid * 16 + lo), lp);
        }
      }
      asm volatile("s_waitcnt vmcnt(0)" ::: "memory");
      __syncthreads();
      if (tid == 0) st_agent(flagA + blk * 16, (unsigned)(t + 1));
    }
  } else {
    // ---------------- phase-B blocks ----------------
    const int ebid = (blk - 16) * 4 + w;       // 0..255
    const int eb = lane >> 2, ejj = lane & 3;  // batch, j-slot
    const int ej = ebid * 4 + ejj;
    float h_st = 0.f, c_st = 0.f;
    float biasr[4];
    #pragma unroll
    for (int g = 0; g < 4; ++g) biasr[g] = bias[g * 1024 + ebid * 4 + ejj];

    short8 wBh[32], wBl[32];                   // -> AGPRs (uses are "a" only)
    {
      const int g = lo & 3, jj = lo >> 2;
      const short* wrH = WhH + (size_t)(g * 1024 + ebid * 4 + jj) * 1024 + hi4 * 8;
      const short* wrL = WhL + (size_t)(g * 1024 + ebid * 4 + jj) * 1024 + hi4 * 8;
      #pragma unroll
      for (int kc = 0; kc < 32; ++kc) {
        wBh[kc] = *(const short8*)(wrH + kc * 32);
        wBl[kc] = *(const short8*)(wrL + kc * 32);
      }
    }
    __shared__ float z_s[4][16][17];

    for (int t = 0; t < 512; ++t) {
      const int pp = t & 1;
      float4_ zv = *(const float4_*)(zx + (size_t)(eb * 512 + t) * 4096 + ebid * 16 + ejj * 4);
      float mk = mask[eb * 512 + t];

      if (w == 0) {                      // poll: all 16 A-flags >= t+1
        const unsigned tgt = (unsigned)(t + 1);
        for (;;) {
          unsigned v = 0xFFFFFFFFu;
          if (lane < 16) v = ld_flag(flagA + lane * 16);
          if (__all((int)(v >= tgt))) break;
          __builtin_amdgcn_s_sleep(1);
        }
      }
      __syncthreads();
      __builtin_amdgcn_sched_barrier(0);

      const short* mrH = mbH + pp * 16384 + lo * 1024 + hi4 * 8;
      const short* mrL = mbL + pp * 16384 + lo * 1024 + hi4 * 8;
      float4_ b0 = {0,0,0,0}, b1 = {0,0,0,0}, b2 = {0,0,0,0};
      float4_ b3 = {0,0,0,0}, b4 = {0,0,0,0}, b5 = {0,0,0,0};
      #pragma unroll
      for (int kc = 0; kc < 32; kc += 2) {
        short8 fh0 = ld16_coh(mrH + (kc + 0) * 32);
        short8 fl0 = ld16_coh(mrL + (kc + 0) * 32);
        short8 fh1 = ld16_coh(mrH + (kc + 1) * 32);
        short8 fl1 = ld16_coh(mrL + (kc + 1) * 32);
        mfma_aw(b0, fh0, wBh[kc + 0]);
        mfma_aw(b1, fl0, wBh[kc + 0]);
        mfma_aw(b2, fh0, wBl[kc + 0]);
        mfma_aw(b3, fh1, wBh[kc + 1]);
        mfma_aw(b4, fl1, wBh[kc + 1]);
        mfma_aw(b5, fh1, wBl[kc + 1]);
      }
      ACC_FENCE(b0, b1, b2, b3, b4, b5);
      float4_ zres = ((b0 + b1) + (b2 + b3)) + (b4 + b5);
      #pragma unroll
      for (int i = 0; i < 4; ++i) z_s[w][hi4 * 4 + i][lo] = zres[i];
      asm volatile("s_waitcnt lgkmcnt(0)" ::: "memory");

      float zg[4];
      #pragma unroll
      for (int g = 0; g < 4; ++g)
        zg[g] = z_s[w][eb][ejj * 4 + g] + zv[g] + biasr[g];
      float ig = sigf(zg[0]), fg = sigf(zg[1]), og = sigf(zg[2]);
      float ug = tanhfast(zg[3]);
      float cn = fg * c_st + ig * ug;
      float hn = og * tanhfast(cn);
      hn = mk * hn + (1.f - mk) * h_st;
      cn = mk * cn + (1.f - mk) * c_st;
      h_st = hn; c_st = cn;

      short hh = f2bf(hn);
      short hl = f2bf(hn - bf2f((unsigned short)hh));
      unsigned hv = (unsigned short)hh, lv2 = (unsigned short)hl;
      unsigned hp = hv  | (((unsigned)__shfl_xor((int)hv, 1)) << 16);
      unsigned lp = lv2 | (((unsigned)__shfl_xor((int)lv2, 1)) << 16);
      if ((ejj & 1) == 0) {
        st_agent((unsigned*)(hbH + pp * 16384 + eb * 1024 + ej), hp);
        st_agent((unsigned*)(hbL + pp * 16384 + eb * 1024 + ej), lp);
      }
      asm volatile("s_waitcnt vmcnt(0)" ::: "memory");
      __syncthreads();
      if (tid == 0) st_agent(flagB + (blk - 16) * 16, (unsigned)(t + 1));
      // out store AFTER the release: off the critical path
      out[(size_t)(eb * 512 + t) * 1024 + ej] = hn;
    }
    out[HSZ + eb * 1024 + ej] = h_st;
    out[HSZ + 16384 + eb * 1024 + ej] = c_st;
  }
}

// ---------------------------------------------------------------------------
extern "C" void kernel_launch(void* const* d_in, const int* in_sizes, int n_in,
                              void* d_out, int out_size, void* d_ws, size_t ws_size,
                              hipStream_t stream)
{
  (void)in_sizes; (void)n_in; (void)out_size; (void)ws_size;
  const float* x     = (const float*)d_in[0];
  const float* mask  = (const float*)d_in[1];
  const float* wmx_v = (const float*)d_in[2];
  const float* wmx_g = (const float*)d_in[3];
  const float* wmh_v = (const float*)d_in[4];
  const float* wmh_g = (const float*)d_in[5];
  const float* wx_v  = (const float*)d_in[6];
  const float* wx_g  = (const float*)d_in[7];
  const float* wh_v  = (const float*)d_in[8];
  const float* wh_g  = (const float*)d_in[9];
  const float* wh_b  = (const float*)d_in[10];

  char* ws = (char*)d_ws;
  const size_t FLAGA_OFF = 0;                      // 16 x 64B = 1 KB
  const size_t FLAGB_OFF = 1024;                   // 64 x 64B = 4 KB
  const size_t HBH_OFF   = 8192;                   // 64 KB each
  const size_t HBL_OFF   = HBH_OFF + 65536;
  const size_t MBH_OFF   = HBL_OFF + 65536;
  const size_t MBL_OFF   = MBH_OFF + 65536;
  const size_t WMHH_OFF  = (size_t)1  << 20;       // 2 MB
  const size_t WMHL_OFF  = (size_t)3  << 20;       // 2 MB
  const size_t WHH_OFF   = (size_t)5  << 20;       // 8 MB
  const size_t WHL_OFF   = (size_t)13 << 20;       // 8 MB
  const size_t WMXH_OFF  = (size_t)21 << 20;       // 1 MB
  const size_t WMXL_OFF  = (size_t)22 << 20;       // 1 MB
  const size_t WXH_OFF   = (size_t)23 << 20;       // 4 MB
  const size_t WXL_OFF   = (size_t)27 << 20;       // 4 MB
  const size_t MX_OFF    = (size_t)32 << 20;       // 32 MB fp32
  const size_t ZX_OFF    = (size_t)64 << 20;       // 128 MB fp32

  unsigned* flagA = (unsigned*)(ws + FLAGA_OFF);
  unsigned* flagB = (unsigned*)(ws + FLAGB_OFF);
  short* hbH = (short*)(ws + HBH_OFF);
  short* hbL = (short*)(ws + HBL_OFF);
  short* mbH = (short*)(ws + MBH_OFF);
  short* mbL = (short*)(ws + MBL_OFF);
  short* WmhH = (short*)(ws + WMHH_OFF);
  short* WmhL = (short*)(ws + WMHL_OFF);
  short* WhH  = (short*)(ws + WHH_OFF);
  short* WhL  = (short*)(ws + WHL_OFF);
  short* WmxH = (short*)(ws + WMXH_OFF);
  short* WmxL = (short*)(ws + WMXL_OFF);
  short* WxH  = (short*)(ws + WXH_OFF);
  short* WxL  = (short*)(ws + WXL_OFF);
  float* mx_f = (float*)(ws + MX_OFF);
  float* zx_f = (float*)(ws + ZX_OFF);
  float* out  = (float*)d_out;

  // zero flags + h/m staging (h0 = 0)
  hipMemsetAsync(ws, 0, MBL_OFF + 65536, stream);

  wnorm_kernel<<<1024, 256, 0, stream>>>(wmx_v, wmx_g, WmxH, WmxL, 512, 0);
  wnorm_kernel<<<1024, 256, 0, stream>>>(wmh_v, wmh_g, WmhH, WmhL, 1024, 0);
  wnorm_kernel<<<4096, 256, 0, stream>>>(wx_v,  wx_g,  WxH,  WxL,  512, 1);
  wnorm_kernel<<<4096, 256, 0, stream>>>(wh_v,  wh_g,  WhH,  WhL,  1024, 0);

  gemm_xw<1024><<<64 * 16, 256, 0, stream>>>(x, WmxH, WmxL, mx_f);
  gemm_xw<4096><<<64 * 64, 256, 0, stream>>>(x, WxH,  WxL,  zx_f);

  scan_kernel<<<80, 256, 0, stream>>>(mx_f, zx_f, mask, WmhH, WmhL, WhH, WhL,
                                      wh_b, hbH, hbL, mbH, mbL, out, flagA, flagB);
}